// Round 1
// baseline (602.613 us; speedup 1.0000x reference)
//
#include <hip/hip_runtime.h>
#include <math.h>

#define BATCH 4
#define CH    256
#define HH    80
#define WW    80
#define HW    (HH*WW)        // 6400
#define NPIX  (BATCH*HW)     // 25600
#define KK    9
#define CO    18             // 2*K*K offset channels
#define KTOT  (KK*CH)        // 2304

// ---------------- x NCHW -> NHWC ----------------
__global__ __launch_bounds__(256) void k_transpose_x(const float* __restrict__ x,
                                                     float* __restrict__ xt) {
    __shared__ float tile[32][33];
    int b  = blockIdx.z;
    int c0 = blockIdx.y * 32;
    int p0 = blockIdx.x * 32;
    int tx = threadIdx.x;   // 0..31
    int ty = threadIdx.y;   // 0..7
    const float* xb = x + (size_t)b * CH * HW;
    #pragma unroll
    for (int i = 0; i < 32; i += 8)
        tile[ty + i][tx] = xb[(size_t)(c0 + ty + i) * HW + p0 + tx];
    __syncthreads();
    float* xtb = xt + (size_t)b * HW * CH;
    #pragma unroll
    for (int i = 0; i < 32; i += 8)
        xtb[(size_t)(p0 + ty + i) * CH + c0 + tx] = tile[tx][ty + i];
}

// ---------------- dcn_w [o][c][kk] -> wt [kk*256+c][o] ----------------
__global__ __launch_bounds__(256) void k_transpose_w(const float* __restrict__ w,
                                                     float* __restrict__ wt) {
    int n = blockIdx.x * 256 + threadIdx.x;   // n = kk*65536 + c*256 + o
    if (n >= KK * CH * CH) return;
    int o  = n & 255;
    int c  = (n >> 8) & 255;
    int kk = n >> 16;
    wt[n] = w[((size_t)(o * CH + c)) * KK + kk];
}

// ---------------- offset conv: off[pix][18] ----------------
__global__ __launch_bounds__(256) void k_offset(const float* __restrict__ x,
                                                const float* __restrict__ ow,
                                                const float* __restrict__ ob,
                                                float* __restrict__ off) {
    __shared__ float red[64][4][CO];
    int t = threadIdx.x;
    int p = t & 63, g = t >> 6;
    int pix = blockIdx.x * 64 + p;
    int b = pix / HW;
    int hw = pix % HW;
    int h = hw / WW, w = hw % WW;
    const float* xb = x + (size_t)b * CH * HW;

    float acc[CO];
    #pragma unroll
    for (int o = 0; o < CO; ++o) acc[o] = 0.f;

    for (int ci = 0; ci < 64; ++ci) {
        int c = g * 64 + ci;
        const float* xc = xb + (size_t)c * HW;
        float v[9];
        #pragma unroll
        for (int dy = 0; dy < 3; ++dy)
            #pragma unroll
            for (int dx = 0; dx < 3; ++dx) {
                int yy = h + dy - 1, xx = w + dx - 1;
                bool ok = (yy >= 0) && (yy < HH) && (xx >= 0) && (xx < WW);
                v[dy * 3 + dx] = ok ? xc[yy * WW + xx] : 0.f;
            }
        const float* wc = ow + (size_t)c * KK;
        #pragma unroll
        for (int o = 0; o < CO; ++o) {
            const float* wo = wc + (size_t)o * CH * KK;
            float s = 0.f;
            #pragma unroll
            for (int tap = 0; tap < 9; ++tap) s = fmaf(v[tap], wo[tap], s);
            acc[o] += s;
        }
    }
    #pragma unroll
    for (int o = 0; o < CO; ++o) red[p][g][o] = acc[o];
    __syncthreads();
    if (t < 64) {
        int opix = blockIdx.x * 64 + t;
        #pragma unroll
        for (int o = 0; o < CO; ++o) {
            float s = red[t][0][o] + red[t][1][o] + red[t][2][o] + red[t][3][o] + ob[o];
            off[(size_t)opix * CO + o] = s;
        }
    }
}

// ---------------- fused deform-gather + GEMM + BN/SiLU/residual ----------------
// block: 256 threads, 64 pixels x 256 out-channels
// thread micro-tile: 16 px x 4 o  (o4 = (t&63)*4, pg = t>>6)
__global__ __launch_bounds__(256) void k_main(const float* __restrict__ x,
                                              const float* __restrict__ xt,
                                              const float* __restrict__ wt,
                                              const float* __restrict__ off,
                                              const float* __restrict__ gamma,
                                              const float* __restrict__ beta,
                                              const float* __restrict__ mean,
                                              const float* __restrict__ var,
                                              float* __restrict__ out) {
    __shared__ int   cbase[64][KK][4];   // 9216 B
    __shared__ float cwt[64][KK][4];     // 9216 B
    __shared__ float wlds[32 * 256];     // 32768 B
    __shared__ float vlds[32 * 68];      // 8704 B  (k' stride 68 floats)

    int t = threadIdx.x;
    int pixbase = blockIdx.x * 64;
    int b = pixbase / HW;

    // --- precompute bilinear corners/weights for 64 px x 9 taps ---
    for (int task = t; task < 64 * KK; task += 256) {
        int p = task / KK, tap = task % KK;
        int pix = pixbase + p;
        int hw = pix % HW;
        int h = hw / WW, w = hw % WW;
        float dy = off[(size_t)pix * CO + 2 * tap];
        float dx = off[(size_t)pix * CO + 2 * tap + 1];
        int ki = tap / 3, kj = tap % 3;
        float py = dy + (float)(h - 1 + ki);
        float px = dx + (float)(w - 1 + kj);
        float y0f = floorf(py), x0f = floorf(px);
        float wy = py - y0f, wx = px - x0f;
        int y0 = (int)y0f, x0 = (int)x0f;
        #pragma unroll
        for (int cy = 0; cy < 2; ++cy)
            #pragma unroll
            for (int cx = 0; cx < 2; ++cx) {
                int yy = y0 + cy, xx = x0 + cx;
                bool ok = (yy >= 0) && (yy < HH) && (xx >= 0) && (xx < WW);
                int yc = min(max(yy, 0), HH - 1);
                int xc = min(max(xx, 0), WW - 1);
                float wgt = (cy ? wy : 1.f - wy) * (cx ? wx : 1.f - wx);
                cbase[p][tap][cy * 2 + cx] = (yc * WW + xc) * CH;
                cwt[p][tap][cy * 2 + cx]   = ok ? wgt : 0.f;
            }
    }
    __syncthreads();

    float acc[16][4];
    #pragma unroll
    for (int i = 0; i < 16; ++i)
        #pragma unroll
        for (int j = 0; j < 4; ++j) acc[i][j] = 0.f;

    const float* xtb = xt + (size_t)b * HW * CH;
    int o4 = (t & 63) * 4;
    int pg = t >> 6;

    for (int kc = 0; kc < 72; ++kc) {
        int tap = kc >> 3;
        int c0  = (kc & 7) * 32;
        __syncthreads();   // previous-iteration readers done before overwrite

        // stage B: weight tile [32 k'][256 o]
        {
            const float4* s4 = (const float4*)(wt + ((size_t)(tap * CH + c0)) * CH);
            float4* d4 = (float4*)wlds;
            #pragma unroll
            for (int r = 0; r < 8; ++r) d4[r * 256 + t] = s4[r * 256 + t];
        }
        // stage A: gather vals [32 k'][64 px]
        {
            int p = t >> 2, cq = t & 3;
            const int*   cb = &cbase[p][tap][0];
            const float* cw = &cwt[p][tap][0];
            float v[8];
            #pragma unroll
            for (int i = 0; i < 8; ++i) v[i] = 0.f;
            #pragma unroll
            for (int corner = 0; corner < 4; ++corner) {
                const float* src = xtb + cb[corner] + c0 + cq * 8;
                float wgt = cw[corner];
                float4 a  = *(const float4*)src;
                float4 bq = *(const float4*)(src + 4);
                v[0] = fmaf(a.x,  wgt, v[0]); v[1] = fmaf(a.y,  wgt, v[1]);
                v[2] = fmaf(a.z,  wgt, v[2]); v[3] = fmaf(a.w,  wgt, v[3]);
                v[4] = fmaf(bq.x, wgt, v[4]); v[5] = fmaf(bq.y, wgt, v[5]);
                v[6] = fmaf(bq.z, wgt, v[6]); v[7] = fmaf(bq.w, wgt, v[7]);
            }
            #pragma unroll
            for (int i = 0; i < 8; ++i) vlds[(cq * 8 + i) * 68 + p] = v[i];
        }
        __syncthreads();

        // compute: 32 k' x (16 px x 4 o)
        #pragma unroll 4
        for (int k2 = 0; k2 < 32; ++k2) {
            float wv[4];
            *(float4*)wv = *(const float4*)(wlds + k2 * 256 + o4);
            float av[16];
            #pragma unroll
            for (int q = 0; q < 4; ++q)
                *(float4*)(av + 4 * q) = *(const float4*)(vlds + k2 * 68 + pg * 16 + 4 * q);
            #pragma unroll
            for (int i = 0; i < 16; ++i) {
                float a = av[i];
                acc[i][0] = fmaf(a, wv[0], acc[i][0]);
                acc[i][1] = fmaf(a, wv[1], acc[i][1]);
                acc[i][2] = fmaf(a, wv[2], acc[i][2]);
                acc[i][3] = fmaf(a, wv[3], acc[i][3]);
            }
        }
    }

    // --- epilogue: BN + SiLU + residual, direct writes ---
    {
        int pb = (pixbase % HW) + pg * 16;
        #pragma unroll
        for (int j = 0; j < 4; ++j) {
            int o = o4 + j;
            float sc = gamma[o] * rsqrtf(var[o] + 1e-5f);
            float mn = mean[o], bt = beta[o];
            const float* xr  = x   + ((size_t)b * CH + o) * HW + pb;
            float*       orow = out + ((size_t)b * CH + o) * HW + pb;
            #pragma unroll
            for (int i = 0; i < 16; ++i) {
                float yv = fmaf(acc[i][j] - mn, sc, bt);
                float s  = yv * (1.f / (1.f + __expf(-yv)));
                orow[i] = xr[i] + s;
            }
        }
    }
}

extern "C" void kernel_launch(void* const* d_in, const int* in_sizes, int n_in,
                              void* d_out, int out_size, void* d_ws, size_t ws_size,
                              hipStream_t stream) {
    const float* x        = (const float*)d_in[0];
    const float* offset_w = (const float*)d_in[1];
    const float* offset_b = (const float*)d_in[2];
    const float* dcn_w    = (const float*)d_in[3];
    const float* gamma    = (const float*)d_in[4];
    const float* beta     = (const float*)d_in[5];
    const float* mean     = (const float*)d_in[6];
    const float* var      = (const float*)d_in[7];
    float* out = (float*)d_out;

    float* xt  = (float*)d_ws;                    // B*HW*CH      = 6,553,600 f
    float* wt  = xt  + (size_t)BATCH * HW * CH;   // KK*CH*CH     =   589,824 f
    float* off = wt  + (size_t)KK * CH * CH;      // NPIX*CO      =   460,800 f

    k_transpose_x<<<dim3(HW / 32, CH / 32, BATCH), dim3(32, 8), 0, stream>>>(x, xt);
    k_transpose_w<<<(KK * CH * CH + 255) / 256, 256, 0, stream>>>(dcn_w, wt);
    k_offset<<<NPIX / 64, 256, 0, stream>>>(x, offset_w, offset_b, off);
    k_main<<<NPIX / 64, 256, 0, stream>>>(x, xt, wt, off, gamma, beta, mean, var, out);
}

// Round 2
// 256.833 us; speedup vs baseline: 2.3463x; 2.3463x over previous
//
#include <hip/hip_runtime.h>
#include <math.h>
#include <stdint.h>

#define BATCH 4
#define CH    256
#define HH    80
#define WW    80
#define HW    (HH*WW)        // 6400
#define NPIX  (BATCH*HW)     // 25600
#define KK    9
#define CO    18             // 2*K*K offset channels
#define NCHUNK 72            // 9 taps * 8 groups of 32 channels
#define WROW  40             // padded K-stride (elements) for LDS tiles (80 B)

typedef _Float16 half8 __attribute__((ext_vector_type(8)));
typedef float    f32x4 __attribute__((ext_vector_type(4)));

// ---------------- x NCHW f32 -> xt NHWC f16 ----------------
__global__ __launch_bounds__(256) void k_transpose_x(const float* __restrict__ x,
                                                     _Float16* __restrict__ xt) {
    __shared__ float tile[32][33];
    int b  = blockIdx.z;
    int c0 = blockIdx.y * 32;
    int p0 = blockIdx.x * 32;
    int tx = threadIdx.x;   // 0..31
    int ty = threadIdx.y;   // 0..7
    const float* xb = x + (size_t)b * CH * HW;
    #pragma unroll
    for (int i = 0; i < 32; i += 8)
        tile[ty + i][tx] = xb[(size_t)(c0 + ty + i) * HW + p0 + tx];
    __syncthreads();
    _Float16* xtb = xt + (size_t)b * HW * CH;
    #pragma unroll
    for (int i = 0; i < 32; i += 8)
        xtb[(size_t)(p0 + ty + i) * CH + c0 + tx] = (_Float16)tile[tx][ty + i];
}

// ---------------- dcn_w [o][c][tap] f32 -> wpack [chunk][o][WROW] f16 ----------------
__global__ __launch_bounds__(256) void k_pack_w(const float* __restrict__ w,
                                                _Float16* __restrict__ wp) {
    int idx = blockIdx.x * 256 + threadIdx.x;
    if (idx >= NCHUNK * CH * WROW) return;
    int kq  = idx % WROW;
    int o   = (idx / WROW) % CH;
    int q   = idx / (WROW * CH);
    int tap = q >> 3;
    int c   = (q & 7) * 32 + kq;
    float v = (kq < 32) ? w[((size_t)o * CH + c) * KK + tap] : 0.f;
    wp[idx] = (_Float16)v;
}

// ---------------- offset conv: off[pix][18] ----------------
__global__ __launch_bounds__(256) void k_offset(const float* __restrict__ x,
                                                const float* __restrict__ ow,
                                                const float* __restrict__ ob,
                                                float* __restrict__ off) {
    __shared__ float red[64][4][CO];
    int t = threadIdx.x;
    int p = t & 63, g = t >> 6;
    int pix = blockIdx.x * 64 + p;
    int b = pix / HW;
    int hw = pix % HW;
    int h = hw / WW, w = hw % WW;
    const float* xb = x + (size_t)b * CH * HW;

    float acc[CO];
    #pragma unroll
    for (int o = 0; o < CO; ++o) acc[o] = 0.f;

    for (int ci = 0; ci < 64; ++ci) {
        int c = g * 64 + ci;
        const float* xc = xb + (size_t)c * HW;
        float v[9];
        #pragma unroll
        for (int dy = 0; dy < 3; ++dy)
            #pragma unroll
            for (int dx = 0; dx < 3; ++dx) {
                int yy = h + dy - 1, xx = w + dx - 1;
                bool ok = (yy >= 0) && (yy < HH) && (xx >= 0) && (xx < WW);
                v[dy * 3 + dx] = ok ? xc[yy * WW + xx] : 0.f;
            }
        const float* wc = ow + (size_t)c * KK;
        #pragma unroll
        for (int o = 0; o < CO; ++o) {
            const float* wo = wc + (size_t)o * CH * KK;
            float s = 0.f;
            #pragma unroll
            for (int tap = 0; tap < 9; ++tap) s = fmaf(v[tap], wo[tap], s);
            acc[o] += s;
        }
    }
    #pragma unroll
    for (int o = 0; o < CO; ++o) red[p][g][o] = acc[o];
    __syncthreads();
    if (t < 64) {
        int opix = blockIdx.x * 64 + t;
        #pragma unroll
        for (int o = 0; o < CO; ++o) {
            float s = red[t][0][o] + red[t][1][o] + red[t][2][o] + red[t][3][o] + ob[o];
            off[(size_t)opix * CO + o] = s;
        }
    }
}

// ---------------- fused deform-gather + MFMA GEMM + BN/SiLU/residual ----------------
// block: 256 threads = 4 waves; 64 px x 256 oc; wave wvi owns oc [64*wvi, 64*wvi+64)
__global__ __launch_bounds__(256) void k_main(const float* __restrict__ x,
                                              const _Float16* __restrict__ xt,
                                              const _Float16* __restrict__ wp,
                                              const float* __restrict__ off,
                                              const float* __restrict__ gamma,
                                              const float* __restrict__ beta,
                                              const float* __restrict__ mean,
                                              const float* __restrict__ var,
                                              float* __restrict__ out) {
    __shared__ int      cbase[64][KK][4];      // 9216 B  (corner base, element units)
    __shared__ float    cwt[64][KK][4];        // 9216 B  (corner bilinear weight)
    __shared__ _Float16 Bl[CH * WROW];         // 20480 B (weights tile, row stride 40)
    __shared__ _Float16 Al[64 * WROW];         // 5120 B  (vals tile,   row stride 40)

    int t = threadIdx.x;
    int pixbase = blockIdx.x * 64;
    int bb  = pixbase / HW;
    int hw0 = pixbase % HW;

    // --- precompute bilinear corners/weights: 64 px x 9 taps ---
    for (int task = t; task < 64 * KK; task += 256) {
        int p = task / KK, tap = task % KK;
        int pix = pixbase + p;
        int hw = pix % HW;
        int hc = hw / WW, wc = hw % WW;
        float dy = off[(size_t)pix * CO + 2 * tap];
        float dx = off[(size_t)pix * CO + 2 * tap + 1];
        int ki = tap / 3, kj = tap % 3;
        float py = dy + (float)(hc - 1 + ki);
        float px = dx + (float)(wc - 1 + kj);
        float y0f = floorf(py), x0f = floorf(px);
        float wy = py - y0f, wx = px - x0f;
        int y0 = (int)y0f, x0 = (int)x0f;
        #pragma unroll
        for (int cy = 0; cy < 2; ++cy)
            #pragma unroll
            for (int cx = 0; cx < 2; ++cx) {
                int yy = y0 + cy, xx = x0 + cx;
                bool ok = (yy >= 0) && (yy < HH) && (xx >= 0) && (xx < WW);
                int yc = min(max(yy, 0), HH - 1);
                int xc = min(max(xx, 0), WW - 1);
                float wgt = (cy ? wy : 1.f - wy) * (cx ? wx : 1.f - wx);
                cbase[p][tap][cy * 2 + cx] = (yc * WW + xc) * CH;
                cwt[p][tap][cy * 2 + cx]   = ok ? wgt : 0.f;
            }
    }

    f32x4 acc[4][4];
    #pragma unroll
    for (int mm = 0; mm < 4; ++mm)
        #pragma unroll
        for (int nn = 0; nn < 4; ++nn) acc[mm][nn] = (f32x4)0.f;

    const _Float16* xtb = xt + (size_t)bb * HW * CH;
    int p   = t >> 2, cq = t & 3;          // gather role: pixel p, channel-quad cq
    int lane = t & 63, wvi = t >> 6;       // wave id
    int lm  = lane & 15;
    int kg8 = (lane >> 4) * 8;

    for (int q = 0; q < NCHUNK; ++q) {
        int tap = q >> 3, cg = q & 7;
        __syncthreads();                   // previous chunk fully consumed
        // stage B: [32 k][256 oc] as Bt[oc][40] f16, linear copy (global image == LDS image)
        {
            const uint4* gb = (const uint4*)(wp + (size_t)q * CH * WROW);
            uint4* db = (uint4*)Bl;
            #pragma unroll
            for (int s = 0; s < 5; ++s) db[s * 256 + t] = gb[s * 256 + t];
        }
        // gather A: vals[p][cg*32 + cq*8 .. +8], packed-f16 4-corner blend
        {
            const int*   cb = &cbase[p][tap][0];
            const float* cw = &cwt[p][tap][0];
            half8 vv = {0, 0, 0, 0, 0, 0, 0, 0};
            #pragma unroll
            for (int cn = 0; cn < 4; ++cn) {
                const _Float16* src = xtb + cb[cn] + cg * 32 + cq * 8;
                half8 a = *(const half8*)src;
                vv += a * (_Float16)cw[cn];
            }
            *(half8*)&Al[p * WROW + cq * 8] = vv;
        }
        __syncthreads();
        // MFMA: 16 px-frag x oc-frag per wave
        half8 af[4], bf[4];
        #pragma unroll
        for (int mm = 0; mm < 4; ++mm)
            af[mm] = *(const half8*)&Al[(mm * 16 + lm) * WROW + kg8];
        #pragma unroll
        for (int nn = 0; nn < 4; ++nn)
            bf[nn] = *(const half8*)&Bl[(wvi * 64 + nn * 16 + lm) * WROW + kg8];
        #pragma unroll
        for (int mm = 0; mm < 4; ++mm)
            #pragma unroll
            for (int nn = 0; nn < 4; ++nn)
                acc[mm][nn] = __builtin_amdgcn_mfma_f32_16x16x32_f16(af[mm], bf[nn], acc[mm][nn], 0, 0, 0);
    }

    // --- epilogue: BN + SiLU + residual ---
    // D mapping (16x16x32): col = lane&15 (oc), row = (lane>>4)*4 + r (px)
    const float* xb2 = x   + (size_t)bb * CH * HW;
    float*       ob  = out + (size_t)bb * CH * HW;
    #pragma unroll
    for (int nn = 0; nn < 4; ++nn) {
        int oc = wvi * 64 + nn * 16 + lm;
        float sc = gamma[oc] * rsqrtf(var[oc] + 1e-5f);
        float mn = mean[oc], bt = beta[oc];
        const float* xr   = xb2 + (size_t)oc * HW + hw0;
        float*       orow = ob  + (size_t)oc * HW + hw0;
        #pragma unroll
        for (int mm = 0; mm < 4; ++mm) {
            #pragma unroll
            for (int r = 0; r < 4; ++r) {
                int px = mm * 16 + (kg8 >> 1) + r;   // (lane>>4)*4 + r
                float yv = (acc[mm][nn][r] - mn) * sc + bt;
                float s  = yv * __builtin_amdgcn_rcpf(1.f + __expf(-yv));
                orow[px] = xr[px] + s;
            }
        }
    }
}

extern "C" void kernel_launch(void* const* d_in, const int* in_sizes, int n_in,
                              void* d_out, int out_size, void* d_ws, size_t ws_size,
                              hipStream_t stream) {
    const float* x        = (const float*)d_in[0];
    const float* offset_w = (const float*)d_in[1];
    const float* offset_b = (const float*)d_in[2];
    const float* dcn_w    = (const float*)d_in[3];
    const float* gamma    = (const float*)d_in[4];
    const float* beta     = (const float*)d_in[5];
    const float* mean     = (const float*)d_in[6];
    const float* var      = (const float*)d_in[7];
    float* out = (float*)d_out;

    _Float16* xt  = (_Float16*)d_ws;                        // NPIX*CH f16      = 13,107,200 B
    _Float16* wpk = xt + (size_t)NPIX * CH;                 // 72*256*40 f16    =  1,474,560 B
    float*    off = (float*)(wpk + (size_t)NCHUNK * CH * WROW);  // NPIX*18 f32 =  1,843,200 B

    k_transpose_x<<<dim3(HW / 32, CH / 32, BATCH), dim3(32, 8), 0, stream>>>(x, xt);
    k_pack_w<<<(NCHUNK * CH * WROW + 255) / 256, 256, 0, stream>>>(dcn_w, wpk);
    k_offset<<<NPIX / 64, 256, 0, stream>>>(x, offset_w, offset_b, off);
    k_main<<<NPIX / 64, 256, 0, stream>>>(x, xt, wpk, off, gamma, beta, mean, var, out);
}

// Round 3
// 136.435 us; speedup vs baseline: 4.4168x; 1.8825x over previous
//
#include <hip/hip_runtime.h>
#include <math.h>
#include <stdint.h>

#define BATCH 4
#define CH    256
#define HH    80
#define WW    80
#define HW    (HH*WW)        // 6400
#define NPIX  (BATCH*HW)     // 25600
#define KK    9
#define CO    18             // 2*K*K offset channels
#define NCHUNK 72            // 9 taps * 8 groups of 32 channels
#define WROW  40             // padded K-stride (elements) for LDS weight tile (80 B)

typedef _Float16 half8 __attribute__((ext_vector_type(8)));
typedef float    f32x4 __attribute__((ext_vector_type(4)));

// ---------------- x NCHW f32 -> xt NHWC f16 ----------------
__global__ __launch_bounds__(256) void k_transpose_x(const float* __restrict__ x,
                                                     _Float16* __restrict__ xt) {
    __shared__ float tile[32][33];
    int b  = blockIdx.z;
    int c0 = blockIdx.y * 32;
    int p0 = blockIdx.x * 32;
    int tx = threadIdx.x;   // 0..31
    int ty = threadIdx.y;   // 0..7
    const float* xb = x + (size_t)b * CH * HW;
    #pragma unroll
    for (int i = 0; i < 32; i += 8)
        tile[ty + i][tx] = xb[(size_t)(c0 + ty + i) * HW + p0 + tx];
    __syncthreads();
    _Float16* xtb = xt + (size_t)b * HW * CH;
    #pragma unroll
    for (int i = 0; i < 32; i += 8)
        xtb[(size_t)(p0 + ty + i) * CH + c0 + tx] = (_Float16)tile[tx][ty + i];
}

// ---------------- dcn_w [o][c][tap] f32 -> wpack [chunk][o][WROW] f16 ----------------
__global__ __launch_bounds__(256) void k_pack_w(const float* __restrict__ w,
                                                _Float16* __restrict__ wp) {
    int idx = blockIdx.x * 256 + threadIdx.x;
    if (idx >= NCHUNK * CH * WROW) return;
    int kq  = idx % WROW;
    int o   = (idx / WROW) % CH;
    int q   = idx / (WROW * CH);
    int tap = q >> 3;
    int c   = (q & 7) * 32 + kq;
    float v = (kq < 32) ? w[((size_t)o * CH + c) * KK + tap] : 0.f;
    wp[idx] = (_Float16)v;
}

// ---------------- offset_w [18][256][9] f32 -> wop [72 chunk][32 oc][32 k] f16 ----------------
__global__ __launch_bounds__(256) void k_pack_ow(const float* __restrict__ ow,
                                                 _Float16* __restrict__ wop) {
    int idx = blockIdx.x * 256 + threadIdx.x;
    if (idx >= NCHUNK * 32 * 32) return;
    int kq = idx & 31;
    int oc = (idx >> 5) & 31;
    int q  = idx >> 10;
    int tap = q >> 3;
    int c   = (q & 7) * 32 + kq;
    float v = (oc < CO) ? ow[((size_t)oc * CH + c) * KK + tap] : 0.f;
    wop[idx] = (_Float16)v;
}

// ---------------- fused offset-conv + deform-gather + MFMA GEMM + BN/SiLU/residual ----------------
// block: 256 threads = 4 waves; 64 px x 256 oc; wave wvi owns oc [64*wvi, 64*wvi+64)
__global__ __launch_bounds__(256) void k_main(const float* __restrict__ x,
                                              const _Float16* __restrict__ xt,
                                              const _Float16* __restrict__ wp,
                                              const _Float16* __restrict__ wop,
                                              const float* __restrict__ obias,
                                              const float* __restrict__ gamma,
                                              const float* __restrict__ beta,
                                              const float* __restrict__ mean,
                                              const float* __restrict__ var,
                                              float* __restrict__ out) {
    __shared__ int      cbase[64][KK][4];      // 9216 B
    __shared__ float    cwt[64][KK][4];        // 9216 B
    __shared__ _Float16 Bl[CH * WROW];         // 20480 B (weights tile, row stride 40)
    __shared__ _Float16 Al[64 * WROW];         // 5120 B  (vals tile,   row stride 40)
    __shared__ float    offl[64][CO];          // 4608 B  (per-pixel offsets)

    int t = threadIdx.x;
    int pixbase = blockIdx.x * 64;
    int bb  = pixbase / HW;
    int hw0 = pixbase % HW;

    int lane = t & 63, wvi = t >> 6;
    int lm  = lane & 15;
    int kg8 = (lane >> 4) * 8;

    const _Float16* xtb = xt + (size_t)bb * HW * CH;

    // ---- phase 1: offset conv via MFMA (wave wvi -> px [wvi*16, wvi*16+16)) ----
    {
        f32x4 oacc0 = (f32x4)0.f, oacc1 = (f32x4)0.f;
        int apx = (pixbase + wvi * 16 + lm) % HW;     // A-row pixel (within batch image)
        int h = apx / WW, w = apx % WW;
        #pragma unroll
        for (int tap = 0; tap < KK; ++tap) {
            int ki = tap / 3, kj = tap % 3;
            int yy = h + ki - 1, xx = w + kj - 1;
            bool ok = (yy >= 0) && (yy < HH) && (xx >= 0) && (xx < WW);
            const _Float16* asrc = xtb + (size_t)(yy * WW + xx) * CH + kg8;
            const _Float16* bsrc = wop + (size_t)(tap * 8 * 32 + lm) * 32 + kg8;
            #pragma unroll
            for (int cg = 0; cg < 8; ++cg) {
                half8 a = {0, 0, 0, 0, 0, 0, 0, 0};
                if (ok) a = *(const half8*)(asrc + cg * 32);
                half8 b0 = *(const half8*)(bsrc + cg * 1024);
                half8 b1 = *(const half8*)(bsrc + cg * 1024 + 16 * 32);
                oacc0 = __builtin_amdgcn_mfma_f32_16x16x32_f16(a, b0, oacc0, 0, 0, 0);
                oacc1 = __builtin_amdgcn_mfma_f32_16x16x32_f16(a, b1, oacc1, 0, 0, 0);
            }
        }
        // D: px = wvi*16 + (lane>>4)*4 + r, oc = lm (+16)
        int prow = wvi * 16 + (lane >> 4) * 4;
        {
            float bias = obias[lm];        // lm < 16 < 18 always valid
            #pragma unroll
            for (int r = 0; r < 4; ++r) offl[prow + r][lm] = oacc0[r] + bias;
        }
        if (lm + 16 < CO) {
            float bias = obias[lm + 16];
            #pragma unroll
            for (int r = 0; r < 4; ++r) offl[prow + r][lm + 16] = oacc1[r] + bias;
        }
    }
    __syncthreads();

    // ---- phase 2: precompute bilinear corners/weights: 64 px x 9 taps ----
    for (int task = t; task < 64 * KK; task += 256) {
        int p = task / KK, tap = task % KK;
        int pix = pixbase + p;
        int hw = pix % HW;
        int hc = hw / WW, wc = hw % WW;
        float dy = offl[p][2 * tap];
        float dx = offl[p][2 * tap + 1];
        int ki = tap / 3, kj = tap % 3;
        float py = dy + (float)(hc - 1 + ki);
        float px = dx + (float)(wc - 1 + kj);
        float y0f = floorf(py), x0f = floorf(px);
        float wy = py - y0f, wx = px - x0f;
        int y0 = (int)y0f, x0 = (int)x0f;
        #pragma unroll
        for (int cy = 0; cy < 2; ++cy)
            #pragma unroll
            for (int cx = 0; cx < 2; ++cx) {
                int yy = y0 + cy, xx = x0 + cx;
                bool okc = (yy >= 0) && (yy < HH) && (xx >= 0) && (xx < WW);
                int yc = min(max(yy, 0), HH - 1);
                int xc = min(max(xx, 0), WW - 1);
                float wgt = (cy ? wy : 1.f - wy) * (cx ? wx : 1.f - wx);
                cbase[p][tap][cy * 2 + cx] = (yc * WW + xc) * CH;
                cwt[p][tap][cy * 2 + cx]   = okc ? wgt : 0.f;
            }
    }

    f32x4 acc[4][4];
    #pragma unroll
    for (int mm = 0; mm < 4; ++mm)
        #pragma unroll
        for (int nn = 0; nn < 4; ++nn) acc[mm][nn] = (f32x4)0.f;

    int p  = t >> 2, cq = t & 3;          // gather role: pixel p, channel-quad cq

    for (int q = 0; q < NCHUNK; ++q) {
        int tap = q >> 3, cg = q & 7;
        __syncthreads();                   // previous chunk fully consumed
        // stage B: [32 k][256 oc] as Bt[oc][40] f16, linear copy
        {
            const uint4* gb = (const uint4*)(wp + (size_t)q * CH * WROW);
            uint4* db = (uint4*)Bl;
            #pragma unroll
            for (int s = 0; s < 5; ++s) db[s * 256 + t] = gb[s * 256 + t];
        }
        // gather A: vals[p][cg*32 + cq*8 .. +8], packed-f16 4-corner blend
        {
            const int*   cb = &cbase[p][tap][0];
            const float* cw = &cwt[p][tap][0];
            half8 vv = {0, 0, 0, 0, 0, 0, 0, 0};
            #pragma unroll
            for (int cn = 0; cn < 4; ++cn) {
                const _Float16* src = xtb + cb[cn] + cg * 32 + cq * 8;
                half8 a = *(const half8*)src;
                vv += a * (_Float16)cw[cn];
            }
            *(half8*)&Al[p * WROW + cq * 8] = vv;
        }
        __syncthreads();
        // MFMA: 4 px-frags x 4 oc-frags per wave
        half8 af[4], bf[4];
        #pragma unroll
        for (int mm = 0; mm < 4; ++mm)
            af[mm] = *(const half8*)&Al[(mm * 16 + lm) * WROW + kg8];
        #pragma unroll
        for (int nn = 0; nn < 4; ++nn)
            bf[nn] = *(const half8*)&Bl[(wvi * 64 + nn * 16 + lm) * WROW + kg8];
        #pragma unroll
        for (int mm = 0; mm < 4; ++mm)
            #pragma unroll
            for (int nn = 0; nn < 4; ++nn)
                acc[mm][nn] = __builtin_amdgcn_mfma_f32_16x16x32_f16(af[mm], bf[nn], acc[mm][nn], 0, 0, 0);
    }

    // --- epilogue: BN + SiLU + residual ---
    const float* xb2  = x   + (size_t)bb * CH * HW;
    float*       outb = out + (size_t)bb * CH * HW;
    #pragma unroll
    for (int nn = 0; nn < 4; ++nn) {
        int oc = wvi * 64 + nn * 16 + lm;
        float sc = gamma[oc] * rsqrtf(var[oc] + 1e-5f);
        float mn = mean[oc], bt = beta[oc];
        const float* xr   = xb2  + (size_t)oc * HW + hw0;
        float*       orow = outb + (size_t)oc * HW + hw0;
        #pragma unroll
        for (int mm = 0; mm < 4; ++mm) {
            #pragma unroll
            for (int r = 0; r < 4; ++r) {
                int px = mm * 16 + (kg8 >> 1) + r;   // (lane>>4)*4 + r
                float yv = (acc[mm][nn][r] - mn) * sc + bt;
                float s  = yv * __builtin_amdgcn_rcpf(1.f + __expf(-yv));
                orow[px] = xr[px] + s;
            }
        }
    }
}

extern "C" void kernel_launch(void* const* d_in, const int* in_sizes, int n_in,
                              void* d_out, int out_size, void* d_ws, size_t ws_size,
                              hipStream_t stream) {
    const float* x        = (const float*)d_in[0];
    const float* offset_w = (const float*)d_in[1];
    const float* offset_b = (const float*)d_in[2];
    const float* dcn_w    = (const float*)d_in[3];
    const float* gamma    = (const float*)d_in[4];
    const float* beta     = (const float*)d_in[5];
    const float* mean     = (const float*)d_in[6];
    const float* var      = (const float*)d_in[7];
    float* out = (float*)d_out;

    _Float16* xt  = (_Float16*)d_ws;                     // NPIX*CH f16   = 13,107,200 B
    _Float16* wpk = xt  + (size_t)NPIX * CH;             // 72*256*40 f16 =  1,474,560 B
    _Float16* wop = wpk + (size_t)NCHUNK * CH * WROW;    // 72*32*32 f16  =    147,456 B

    k_transpose_x<<<dim3(HW / 32, CH / 32, BATCH), dim3(32, 8), 0, stream>>>(x, xt);
    k_pack_w<<<(NCHUNK * CH * WROW + 255) / 256, 256, 0, stream>>>(dcn_w, wpk);
    k_pack_ow<<<(NCHUNK * 32 * 32 + 255) / 256, 256, 0, stream>>>(offset_w, wop);
    k_main<<<NPIX / 64, 256, 0, stream>>>(x, xt, wpk, wop, offset_b,
                                          gamma, beta, mean, var, out);
}